// Round 4
// baseline (549.426 us; speedup 1.0000x reference)
//
#include <hip/hip_runtime.h>
#include <hip/hip_fp16.h>

// FeatureGrid: trilinear interp of N points into (C=32, 128^3) f32 grid.
// v5: fp16 (S,C) workspace + 3D macro-cell binning (8x8x8 cells, 17^3 bins)
// via deterministic counting sort, then an LDS-staged gather: each block
// stages its bin's 9x9x9 vertex sub-grid (58 KB, stride-80 bank swizzle)
// and serves all corner reads from LDS instead of L2 (~200cyc -> ~12cyc).
// Per-point math order unchanged -> bitwise-identical output to v2/v3/v4.

constexpr int   GD      = 128;                         // grid dim per axis
constexpr long long SPATIAL = (long long)GD * GD * GD; // 2097152
constexpr int   FD      = 32;                          // channels
constexpr float PLO     = -10.0f;
constexpr float PHI     = 10.0f;

constexpr int   NBX     = 17;                          // bins per axis
constexpr int   NBINS   = NBX * NBX * NBX;             // 4913
constexpr int   HBLK    = 512;                         // hist/scatter blocks
constexpr int   VS      = 9;                           // verts per bin axis
constexpr int   VN      = VS * VS * VS;                // 729
constexpr int   VSTRIDE = 80;                          // LDS bytes per vert row

typedef float nfloat4 __attribute__((ext_vector_type(4)));

__device__ __forceinline__ void cell_of(float px, float py, float pz,
                                        int& x0, int& y0, int& z0) {
    const float cx = 2.0f * (px - PLO) / (PHI - PLO) - 1.0f;
    const float cy = 2.0f * (py - PLO) / (PHI - PLO) - 1.0f;
    const float cz = 2.0f * (pz - PLO) / (PHI - PLO) - 1.0f;
    const float fx = ((cx + 1.0f) * GD - 1.0f) * 0.5f;
    const float fy = ((cy + 1.0f) * GD - 1.0f) * 0.5f;
    const float fz = ((cz + 1.0f) * GD - 1.0f) * 0.5f;
    x0 = (int)floorf(fx);
    y0 = (int)floorf(fy);
    z0 = (int)floorf(fz);
}

__device__ __forceinline__ int bin_of(int x0, int y0, int z0) {
    const int bx = min(max((x0 + 1) >> 3, 0), NBX - 1);
    const int by = min(max((y0 + 1) >> 3, 0), NBX - 1);
    const int bz = min(max((z0 + 1) >> 3, 0), NBX - 1);
    return (bz * NBX + by) * NBX + bx;
}

// ---------------- transpose+convert (C,S) f32 -> (S,C) fp16 ----------------
__global__ __launch_bounds__(256) void transpose_feat_h(
    const float* __restrict__ f, __half* __restrict__ o) {
    __shared__ float lds[64][FD + 1];
    const int t  = threadIdx.x;
    const long long s0 = (long long)blockIdx.x * 64;
    const int sl = t & 63;   // spatial within tile
    const int cq = t >> 6;   // 0..3
#pragma unroll
    for (int it = 0; it < 8; ++it) {
        const int c = it * 4 + cq;
        lds[sl][c] =
            __builtin_nontemporal_load(f + (size_t)c * SPATIAL + s0 + sl);
    }
    __syncthreads();
    const int c0 = (t & 15) * 2;  // channel pair
    const int sw = t >> 4;        // 0..15
#pragma unroll
    for (int it = 0; it < 4; ++it) {
        const int s = sw + it * 16;
        __half2 h;
        h.x = __float2half(lds[s][c0]);
        h.y = __float2half(lds[s][c0 + 1]);
        *reinterpret_cast<__half2*>(o + (size_t)(s0 + s) * FD + c0) = h;
    }
}

// ---------------- pass A: per-block 3D-bin histogram ----------------
// blockHist layout block-major: blockHist[blk * NBINS + bin] (coalesced I/O)
__global__ __launch_bounds__(256) void hist3d(
    const float* __restrict__ x, int* __restrict__ blockHist, int npts) {
    __shared__ int h[NBINS];
    const int t = threadIdx.x;
    for (int i = t; i < NBINS; i += 256) h[i] = 0;
    __syncthreads();
    const int stride = gridDim.x * 256;
    for (int n = blockIdx.x * 256 + t; n < npts; n += stride) {
        int x0, y0, z0;
        cell_of(x[3 * n + 0], x[3 * n + 1], x[3 * n + 2], x0, y0, z0);
        atomicAdd(&h[bin_of(x0, y0, z0)], 1);
    }
    __syncthreads();
    int* row = blockHist + (size_t)blockIdx.x * NBINS;
    for (int i = t; i < NBINS; i += 256) row[i] = h[i];
}

// ---------------- pass B1: exclusive scan of each bin across blocks --------
// one block per bin; entries at blockHist[blk*NBINS + bin] (strided, L2-hit).
__global__ __launch_bounds__(256) void scan_rows(
    int* __restrict__ blockHist, int* __restrict__ binSum, int nblk) {
    __shared__ int tmp[256];
    const int bin = blockIdx.x;
    const int t = threadIdx.x;
    int carry = 0;
    for (int base = 0; base < nblk; base += 256) {
        const int blk = base + t;
        const int v = (blk < nblk) ? blockHist[(size_t)blk * NBINS + bin] : 0;
        tmp[t] = v;
        __syncthreads();
        int run = v;
        for (int off = 1; off < 256; off <<= 1) {
            const int add = (t >= off) ? tmp[t - off] : 0;
            __syncthreads();
            run += add;
            tmp[t] = run;
            __syncthreads();
        }
        if (blk < nblk) blockHist[(size_t)blk * NBINS + bin] = carry + (run - v);
        carry += tmp[255];
        __syncthreads();
    }
    if (t == 0) binSum[bin] = carry;
}

// ---------------- pass B2: exclusive scan of bin totals (4913) ----------
// single block, chunked Hillis-Steele with serial carry. binBase[NBINS] = total.
__global__ __launch_bounds__(256) void scan_totals(
    const int* __restrict__ binSum, int* __restrict__ binBase) {
    __shared__ int tmp[256];
    const int t = threadIdx.x;
    int carry = 0;
    for (int base = 0; base < NBINS; base += 256) {
        const int i = base + t;
        const int v = (i < NBINS) ? binSum[i] : 0;
        tmp[t] = v;
        __syncthreads();
        int run = v;
        for (int off = 1; off < 256; off <<= 1) {
            const int add = (t >= off) ? tmp[t - off] : 0;
            __syncthreads();
            run += add;
            tmp[t] = run;
            __syncthreads();
        }
        if (i < NBINS) binBase[i] = carry + (run - v);
        carry += tmp[255];
        __syncthreads();
    }
    if (t == 0) binBase[NBINS] = carry;
}

// ---------------- pass C: atomic-free global scatter ----------------
// rank within (block,bin) via LDS atomics; destination fully determined.
// Intra-bin order is nondeterministic but each point's own computation and
// output slot depend only on the point -> output unaffected.
__global__ __launch_bounds__(256) void scatter3d(
    const float* __restrict__ x, const int* __restrict__ blockHist,
    const int* __restrict__ binBase, nfloat4* __restrict__ binned, int npts) {
    __shared__ int h[NBINS];
    const int t = threadIdx.x;
    for (int i = t; i < NBINS; i += 256) h[i] = 0;
    __syncthreads();
    const int* row = blockHist + (size_t)blockIdx.x * NBINS;
    const int stride = gridDim.x * 256;
    for (int n = blockIdx.x * 256 + t; n < npts; n += stride) {
        const float px = x[3 * n + 0];
        const float py = x[3 * n + 1];
        const float pz = x[3 * n + 2];
        int x0, y0, z0;
        cell_of(px, py, pz, x0, y0, z0);
        const int bin = bin_of(x0, y0, z0);
        const int rank = atomicAdd(&h[bin], 1);
        const int dest = binBase[bin] + row[bin] + rank;
        nfloat4 rec = {px, py, pz, __int_as_float(n)};
        binned[dest] = rec;
    }
}

// ---------------- pass D: LDS-staged gather, one block per bin ----------
// stage 9^3 verts x 64 B (stride 80 B -> start banks spread over 8 classes,
// ~2-way max conflict = free), then 4 threads/point read corners from LDS.
__global__ __launch_bounds__(256) void trilerp_lds(
    const nfloat4* __restrict__ binned, const __half* __restrict__ ft,
    const int* __restrict__ binBase, float* __restrict__ out) {
    __shared__ __align__(16) unsigned char smem[VN * VSTRIDE];
    const int bin = blockIdx.x;
    const int bx = bin % NBX;
    const int bq = bin / NBX;
    const int by = bq % NBX;
    const int bz = bq / NBX;
    const int vbx = bx * 8 - 1, vby = by * 8 - 1, vbz = bz * 8 - 1;
    const int t = threadIdx.x;

    // ---- stage: 729 verts * 4 chunks of 16 B ----
    for (int i = t; i < VN * 4; i += 256) {
        const int v = i >> 2, ch = i & 3;
        const int lx = v % VS;
        const int vq = v / VS;
        const int ly = vq % VS;
        const int lz = vq / VS;
        const int gx = min(max(vbx + lx, 0), GD - 1);
        const int gy = min(max(vby + ly, 0), GD - 1);
        const int gz = min(max(vbz + lz, 0), GD - 1);
        const size_t src = ((size_t)(gz * GD + gy) * GD + gx) * FD + ch * 8;
        *reinterpret_cast<nfloat4*>(&smem[v * VSTRIDE + ch * 16]) =
            *reinterpret_cast<const nfloat4*>(ft + src);
    }
    __syncthreads();

    const int start = binBase[bin];
    const int end   = binBase[bin + 1];
    const int j = t & 3;  // channel octet

    for (int p = start + (t >> 2); p < end; p += 64) {
        const nfloat4 rec = binned[p];
        const float px = rec.x, py = rec.y, pz = rec.z;
        const int n = __float_as_int(rec.w);

        // match reference arithmetic order
        const float cx = 2.0f * (px - PLO) / (PHI - PLO) - 1.0f;
        const float cy = 2.0f * (py - PLO) / (PHI - PLO) - 1.0f;
        const float cz = 2.0f * (pz - PLO) / (PHI - PLO) - 1.0f;
        const float fx = ((cx + 1.0f) * GD - 1.0f) * 0.5f;
        const float fy = ((cy + 1.0f) * GD - 1.0f) * 0.5f;
        const float fz = ((cz + 1.0f) * GD - 1.0f) * 0.5f;

        const float x0f = floorf(fx), y0f = floorf(fy), z0f = floorf(fz);
        const float wx = fx - x0f, wy = fy - y0f, wz = fz - z0f;
        const int x0 = (int)x0f, y0 = (int)y0f, z0 = (int)z0f;

        // local vert coords; staging already applied the boundary clamp
        const int lx0 = min(max(x0 - vbx, 0), VS - 2);
        const int ly0 = min(max(y0 - vby, 0), VS - 2);
        const int lz0 = min(max(z0 - vbz, 0), VS - 2);

        float acc[8] = {0.f, 0.f, 0.f, 0.f, 0.f, 0.f, 0.f, 0.f};
#pragma unroll
        for (int dz = 0; dz < 2; ++dz) {
#pragma unroll
            for (int dy = 0; dy < 2; ++dy) {
#pragma unroll
                for (int dx = 0; dx < 2; ++dx) {
                    const int xi = x0 + dx, yi = y0 + dy, zi = z0 + dz;
                    const bool valid = ((unsigned)xi < (unsigned)GD) &
                                       ((unsigned)yi < (unsigned)GD) &
                                       ((unsigned)zi < (unsigned)GD);
                    float w = (dx ? wx : 1.0f - wx) * (dy ? wy : 1.0f - wy) *
                              (dz ? wz : 1.0f - wz);
                    w = valid ? w : 0.0f;
                    const int v =
                        ((lz0 + dz) * VS + (ly0 + dy)) * VS + (lx0 + dx);
                    const nfloat4 raw = *reinterpret_cast<const nfloat4*>(
                        &smem[v * VSTRIDE + j * 16]);
                    const __half2* h2 = reinterpret_cast<const __half2*>(&raw);
#pragma unroll
                    for (int k = 0; k < 4; ++k) {
                        const float2 fv = __half22float2(h2[k]);
                        acc[2 * k + 0] = fmaf(fv.x, w, acc[2 * k + 0]);
                        acc[2 * k + 1] = fmaf(fv.y, w, acc[2 * k + 1]);
                    }
                }
            }
        }
        float* op = out + (size_t)n * FD + j * 8;
        nfloat4 o0 = {acc[0], acc[1], acc[2], acc[3]};
        nfloat4 o1 = {acc[4], acc[5], acc[6], acc[7]};
        __builtin_nontemporal_store(o0, reinterpret_cast<nfloat4*>(op));
        __builtin_nontemporal_store(o1, reinterpret_cast<nfloat4*>(op) + 1);
    }
}

// ---------------- fallback: un-binned gather (round-1 kernel) ----------------
__global__ __launch_bounds__(256) void trilerp_h(
    const float* __restrict__ x, const __half* __restrict__ ft,
    float* __restrict__ out, int npts) {
    const int tid = blockIdx.x * 256 + threadIdx.x;
    const int n = tid >> 2;
    if (n >= npts) return;
    const int j = tid & 3;

    const float px = x[3 * n + 0];
    const float py = x[3 * n + 1];
    const float pz = x[3 * n + 2];
    const float cx = 2.0f * (px - PLO) / (PHI - PLO) - 1.0f;
    const float cy = 2.0f * (py - PLO) / (PHI - PLO) - 1.0f;
    const float cz = 2.0f * (pz - PLO) / (PHI - PLO) - 1.0f;
    const float fx = ((cx + 1.0f) * GD - 1.0f) * 0.5f;
    const float fy = ((cy + 1.0f) * GD - 1.0f) * 0.5f;
    const float fz = ((cz + 1.0f) * GD - 1.0f) * 0.5f;
    const float x0f = floorf(fx), y0f = floorf(fy), z0f = floorf(fz);
    const float wx = fx - x0f, wy = fy - y0f, wz = fz - z0f;
    const int x0 = (int)x0f, y0 = (int)y0f, z0 = (int)z0f;

    float acc[8] = {0.f, 0.f, 0.f, 0.f, 0.f, 0.f, 0.f, 0.f};
#pragma unroll
    for (int dz = 0; dz < 2; ++dz)
#pragma unroll
        for (int dy = 0; dy < 2; ++dy)
#pragma unroll
            for (int dx = 0; dx < 2; ++dx) {
                const int xi = x0 + dx, yi = y0 + dy, zi = z0 + dz;
                const bool valid = ((unsigned)xi < (unsigned)GD) &
                                   ((unsigned)yi < (unsigned)GD) &
                                   ((unsigned)zi < (unsigned)GD);
                float w = (dx ? wx : 1.0f - wx) * (dy ? wy : 1.0f - wy) *
                          (dz ? wz : 1.0f - wz);
                w = valid ? w : 0.0f;
                const int xc = min(max(xi, 0), GD - 1);
                const int yc = min(max(yi, 0), GD - 1);
                const int zc = min(max(zi, 0), GD - 1);
                const size_t idx = (size_t)(zc * GD + yc) * GD + xc;
                const nfloat4 raw = *reinterpret_cast<const nfloat4*>(
                    ft + idx * FD + j * 8);
                const __half2* h2 = reinterpret_cast<const __half2*>(&raw);
#pragma unroll
                for (int k = 0; k < 4; ++k) {
                    const float2 fv = __half22float2(h2[k]);
                    acc[2 * k + 0] = fmaf(fv.x, w, acc[2 * k + 0]);
                    acc[2 * k + 1] = fmaf(fv.y, w, acc[2 * k + 1]);
                }
            }
    float* op = out + (size_t)n * FD + j * 8;
    nfloat4 o0 = {acc[0], acc[1], acc[2], acc[3]};
    nfloat4 o1 = {acc[4], acc[5], acc[6], acc[7]};
    __builtin_nontemporal_store(o0, reinterpret_cast<nfloat4*>(op));
    __builtin_nontemporal_store(o1, reinterpret_cast<nfloat4*>(op) + 1);
}

// ---------------- fallback: direct gather in (C,S) layout ----------------
__global__ __launch_bounds__(256) void trilerp_direct(
    const float* __restrict__ x, const float* __restrict__ f,
    float* __restrict__ out, int npts) {
    const int tid = blockIdx.x * 256 + threadIdx.x;
    const int n = tid >> 3;
    if (n >= npts) return;
    const int j = tid & 7;

    const float px = x[3 * n + 0];
    const float py = x[3 * n + 1];
    const float pz = x[3 * n + 2];
    const float cx = 2.0f * (px - PLO) / (PHI - PLO) - 1.0f;
    const float cy = 2.0f * (py - PLO) / (PHI - PLO) - 1.0f;
    const float cz = 2.0f * (pz - PLO) / (PHI - PLO) - 1.0f;
    const float fx = ((cx + 1.0f) * GD - 1.0f) * 0.5f;
    const float fy = ((cy + 1.0f) * GD - 1.0f) * 0.5f;
    const float fz = ((cz + 1.0f) * GD - 1.0f) * 0.5f;
    const float x0f = floorf(fx), y0f = floorf(fy), z0f = floorf(fz);
    const float wx = fx - x0f, wy = fy - y0f, wz = fz - z0f;
    const int x0 = (int)x0f, y0 = (int)y0f, z0 = (int)z0f;

    float acc[4] = {0.f, 0.f, 0.f, 0.f};
#pragma unroll
    for (int dz = 0; dz < 2; ++dz)
#pragma unroll
        for (int dy = 0; dy < 2; ++dy)
#pragma unroll
            for (int dx = 0; dx < 2; ++dx) {
                const int xi = x0 + dx, yi = y0 + dy, zi = z0 + dz;
                const bool valid = ((unsigned)xi < (unsigned)GD) &
                                   ((unsigned)yi < (unsigned)GD) &
                                   ((unsigned)zi < (unsigned)GD);
                float w = (dx ? wx : 1.0f - wx) * (dy ? wy : 1.0f - wy) *
                          (dz ? wz : 1.0f - wz);
                w = valid ? w : 0.0f;
                const int xc = min(max(xi, 0), GD - 1);
                const int yc = min(max(yi, 0), GD - 1);
                const int zc = min(max(zi, 0), GD - 1);
                const size_t idx = (size_t)(zc * GD + yc) * GD + xc;
#pragma unroll
                for (int k = 0; k < 4; ++k)
                    acc[k] = fmaf(f[(size_t)(j * 4 + k) * SPATIAL + idx], w, acc[k]);
            }
#pragma unroll
    for (int k = 0; k < 4; ++k) out[(size_t)n * FD + j * 4 + k] = acc[k];
}

extern "C" void kernel_launch(void* const* d_in, const int* in_sizes, int n_in,
                              void* d_out, int out_size, void* d_ws, size_t ws_size,
                              hipStream_t stream) {
    const float* x    = (const float*)d_in[0];
    const float* feat = (const float*)d_in[1];
    float*       out  = (float*)d_out;
    const int npts = in_sizes[0] / 3;

    const size_t FTH_BYTES    = (size_t)SPATIAL * FD * sizeof(__half); // 128 MiB
    const size_t BINNED_OFF   = FTH_BYTES;
    const size_t BINNED_BYTES = (size_t)npts * 16;
    const size_t BH_OFF   = BINNED_OFF + ((BINNED_BYTES + 255) & ~(size_t)255);
    const size_t BH_BYTES = (size_t)HBLK * NBINS * sizeof(int);       // ~10 MB
    const size_t SUM_OFF  = BH_OFF + ((BH_BYTES + 255) & ~(size_t)255);
    const size_t SUM_BYTES  = (size_t)NBINS * sizeof(int);
    const size_t BASE_OFF = SUM_OFF + ((SUM_BYTES + 255) & ~(size_t)255);
    const size_t BASE_BYTES = (size_t)(NBINS + 1) * sizeof(int);
    const size_t need_binned = BASE_OFF + BASE_BYTES;

    const int gblocks = (npts * 4 + 255) / 256;  // 4 threads / point

    if (ws_size >= need_binned) {
        __half*  fth     = (__half*)d_ws;
        nfloat4* binned  = (nfloat4*)((char*)d_ws + BINNED_OFF);
        int*     bhist   = (int*)((char*)d_ws + BH_OFF);
        int*     binSum  = (int*)((char*)d_ws + SUM_OFF);
        int*     binBase = (int*)((char*)d_ws + BASE_OFF);

        transpose_feat_h<<<(int)(SPATIAL / 64), 256, 0, stream>>>(feat, fth);
        hist3d<<<HBLK, 256, 0, stream>>>(x, bhist, npts);
        scan_rows<<<NBINS, 256, 0, stream>>>(bhist, binSum, HBLK);
        scan_totals<<<1, 256, 0, stream>>>(binSum, binBase);
        scatter3d<<<HBLK, 256, 0, stream>>>(x, bhist, binBase, binned, npts);
        trilerp_lds<<<NBINS, 256, 0, stream>>>(binned, fth, binBase, out);
    } else if (ws_size >= FTH_BYTES) {
        __half* fth = (__half*)d_ws;
        transpose_feat_h<<<(int)(SPATIAL / 64), 256, 0, stream>>>(feat, fth);
        trilerp_h<<<gblocks, 256, 0, stream>>>(x, fth, out, npts);
    } else {
        const int dblocks = (npts * 8 + 255) / 256;
        trilerp_direct<<<dblocks, 256, 0, stream>>>(x, feat, out, npts);
    }
}

// Round 5
// 470.864 us; speedup vs baseline: 1.1668x; 1.1668x over previous
//
#include <hip/hip_runtime.h>
#include <hip/hip_fp16.h>

// FeatureGrid: trilinear interp of N points into (C=32, 128^3) f32 grid.
// v6: fp16 (S,C) workspace + deterministic z-slab counting sort (round-3)
// + XCD-chunked gather swizzle: blocks dispatch round-robin across the 8
// XCDs, so giving XCD k a CONTIGUOUS 1/8 of the z-sorted points makes its
// private 4-MiB L2 hold the ~4-MiB slab window -> corner-line reuse (4x)
// happens in L2 instead of thrashing to L3. Math order unchanged ->
// bitwise-identical output to v2..v5.

constexpr int   GD      = 128;                         // grid dim per axis
constexpr long long SPATIAL = (long long)GD * GD * GD; // 2097152
constexpr int   FD      = 32;                          // channels
constexpr float PLO     = -10.0f;
constexpr float PHI     = 10.0f;
constexpr int   NBUCKET = 129;                         // z0 in [-1,127] -> z0+1

typedef float nfloat4 __attribute__((ext_vector_type(4)));

__device__ __forceinline__ int z_bucket(float pz) {
    const float cz = 2.0f * (pz - PLO) / (PHI - PLO) - 1.0f;
    const float fz = ((cz + 1.0f) * GD - 1.0f) * 0.5f;
    int zb = (int)floorf(fz) + 1;
    return min(max(zb, 0), NBUCKET - 1);
}

// ---------------- transpose+convert (C,S) f32 -> (S,C) fp16 ----------------
__global__ __launch_bounds__(256) void transpose_feat_h(
    const float* __restrict__ f, __half* __restrict__ o) {
    __shared__ float lds[64][FD + 1];
    const int t  = threadIdx.x;
    const long long s0 = (long long)blockIdx.x * 64;
    const int sl = t & 63;   // spatial within tile
    const int cq = t >> 6;   // 0..3
#pragma unroll
    for (int it = 0; it < 8; ++it) {
        const int c = it * 4 + cq;
        lds[sl][c] =
            __builtin_nontemporal_load(f + (size_t)c * SPATIAL + s0 + sl);
    }
    __syncthreads();
    const int c0 = (t & 15) * 2;  // channel pair
    const int sw = t >> 4;        // 0..15
#pragma unroll
    for (int it = 0; it < 4; ++it) {
        const int s = sw + it * 16;
        __half2 h;
        h.x = __float2half(lds[s][c0]);
        h.y = __float2half(lds[s][c0 + 1]);
        *reinterpret_cast<__half2*>(o + (size_t)(s0 + s) * FD + c0) = h;
    }
}

// ---------------- pass A: per-block z-slab histogram ----------------
// blockHist layout is bin-major: blockHist[bin * nblocks + block]
__global__ __launch_bounds__(256) void hist_blocks(
    const float* __restrict__ x, int* __restrict__ blockHist,
    int npts, int nblocks) {
    __shared__ int h[NBUCKET];
    const int t = threadIdx.x;
    if (t < NBUCKET) h[t] = 0;
    __syncthreads();
    const int n = blockIdx.x * 256 + t;
    if (n < npts) atomicAdd(&h[z_bucket(x[3 * n + 2])], 1);
    __syncthreads();
    if (t < NBUCKET)
        blockHist[(size_t)t * nblocks + blockIdx.x] = h[t];
}

// ---------------- pass B1: exclusive scan within each bin row ----------------
__global__ __launch_bounds__(256) void scan_bins(
    int* __restrict__ blockHist, int* __restrict__ binSum, int nblocks) {
    __shared__ int tmp[256];
    const int bin = blockIdx.x;
    int* row = blockHist + (size_t)bin * nblocks;
    const int t = threadIdx.x;
    int carry = 0;
    for (int base = 0; base < nblocks; base += 256) {
        const int i = base + t;
        const int v = (i < nblocks) ? row[i] : 0;
        tmp[t] = v;
        __syncthreads();
        int run = v;
        for (int off = 1; off < 256; off <<= 1) {
            const int add = (t >= off) ? tmp[t - off] : 0;
            __syncthreads();
            run += add;
            tmp[t] = run;
            __syncthreads();
        }
        if (i < nblocks) row[i] = carry + (run - v);  // exclusive + carry
        carry += tmp[255];
        __syncthreads();
    }
    if (t == 0) binSum[bin] = carry;
}

// ---------------- pass B2: scan bin totals (129 entries, trivial) ----------
__global__ void scan_bin_totals(const int* __restrict__ binSum,
                                int* __restrict__ binBase) {
    if (threadIdx.x == 0 && blockIdx.x == 0) {
        int run = 0;
        for (int b = 0; b < NBUCKET; ++b) {
            binBase[b] = run;
            run += binSum[b];
        }
    }
}

// ---------------- pass C: atomic-free global scatter ----------------
__global__ __launch_bounds__(256) void scatter_det(
    const float* __restrict__ x, const int* __restrict__ blockHist,
    const int* __restrict__ binBase, nfloat4* __restrict__ binned,
    int npts, int nblocks) {
    __shared__ int h[NBUCKET];
    const int t = threadIdx.x;
    if (t < NBUCKET) h[t] = 0;
    __syncthreads();
    const int n = blockIdx.x * 256 + t;
    if (n >= npts) return;
    const float px = x[3 * n + 0];
    const float py = x[3 * n + 1];
    const float pz = x[3 * n + 2];
    const int bin = z_bucket(pz);
    const int rank = atomicAdd(&h[bin], 1);
    const int dest =
        binBase[bin] + blockHist[(size_t)bin * nblocks + blockIdx.x] + rank;
    nfloat4 rec = {px, py, pz, __int_as_float(n)};
    binned[dest] = rec;
}

// ---------------- pass D: gather, bucket order, XCD-chunked swizzle --------
// 4 threads per point; each owns 8 channels (16-B load per corner).
// Block swizzle (m204 bijective): blocks dispatch round-robin over 8 XCDs;
// remap so XCD k works a contiguous chunk of the z-sorted point array.
__global__ __launch_bounds__(256) void trilerp_bx(
    const nfloat4* __restrict__ binned, const __half* __restrict__ ft,
    float* __restrict__ out, int npts) {
    const int nwg = gridDim.x;
    const int q = nwg >> 3, r = nwg & 7;
    const int xcd = blockIdx.x & 7;
    const int ord = blockIdx.x >> 3;
    const int wid =
        (xcd < r ? xcd * (q + 1) : r * (q + 1) + (xcd - r) * q) + ord;

    const int tid = wid * 256 + threadIdx.x;
    const int i = tid >> 2;
    if (i >= npts) return;
    const int j = tid & 3;  // channel octet

    const nfloat4 rec = binned[i];
    const float px = rec.x, py = rec.y, pz = rec.z;
    const int n = __float_as_int(rec.w);

    // match reference arithmetic order
    const float cx = 2.0f * (px - PLO) / (PHI - PLO) - 1.0f;
    const float cy = 2.0f * (py - PLO) / (PHI - PLO) - 1.0f;
    const float cz = 2.0f * (pz - PLO) / (PHI - PLO) - 1.0f;
    const float fx = ((cx + 1.0f) * GD - 1.0f) * 0.5f;
    const float fy = ((cy + 1.0f) * GD - 1.0f) * 0.5f;
    const float fz = ((cz + 1.0f) * GD - 1.0f) * 0.5f;

    const float x0f = floorf(fx), y0f = floorf(fy), z0f = floorf(fz);
    const float wx = fx - x0f, wy = fy - y0f, wz = fz - z0f;
    const int x0 = (int)x0f, y0 = (int)y0f, z0 = (int)z0f;

    float acc[8] = {0.f, 0.f, 0.f, 0.f, 0.f, 0.f, 0.f, 0.f};
#pragma unroll
    for (int dz = 0; dz < 2; ++dz) {
#pragma unroll
        for (int dy = 0; dy < 2; ++dy) {
#pragma unroll
            for (int dx = 0; dx < 2; ++dx) {
                const int xi = x0 + dx, yi = y0 + dy, zi = z0 + dz;
                const bool valid = ((unsigned)xi < (unsigned)GD) &
                                   ((unsigned)yi < (unsigned)GD) &
                                   ((unsigned)zi < (unsigned)GD);
                float w = (dx ? wx : 1.0f - wx) * (dy ? wy : 1.0f - wy) *
                          (dz ? wz : 1.0f - wz);
                w = valid ? w : 0.0f;
                const int xc = min(max(xi, 0), GD - 1);
                const int yc = min(max(yi, 0), GD - 1);
                const int zc = min(max(zi, 0), GD - 1);
                const size_t idx = (size_t)(zc * GD + yc) * GD + xc;
                const nfloat4 raw = *reinterpret_cast<const nfloat4*>(
                    ft + idx * FD + j * 8);
                const __half2* h2 = reinterpret_cast<const __half2*>(&raw);
#pragma unroll
                for (int k = 0; k < 4; ++k) {
                    const float2 fv = __half22float2(h2[k]);
                    acc[2 * k + 0] = fmaf(fv.x, w, acc[2 * k + 0]);
                    acc[2 * k + 1] = fmaf(fv.y, w, acc[2 * k + 1]);
                }
            }
        }
    }
    float* op = out + (size_t)n * FD + j * 8;
    nfloat4 o0 = {acc[0], acc[1], acc[2], acc[3]};
    nfloat4 o1 = {acc[4], acc[5], acc[6], acc[7]};
    // write-once stream: keep L2 for the gather
    __builtin_nontemporal_store(o0, reinterpret_cast<nfloat4*>(op));
    __builtin_nontemporal_store(o1, reinterpret_cast<nfloat4*>(op) + 1);
}

// ---------------- fallback: un-binned gather (round-1 kernel) ----------------
__global__ __launch_bounds__(256) void trilerp_h(
    const float* __restrict__ x, const __half* __restrict__ ft,
    float* __restrict__ out, int npts) {
    const int tid = blockIdx.x * 256 + threadIdx.x;
    const int n = tid >> 2;
    if (n >= npts) return;
    const int j = tid & 3;

    const float px = x[3 * n + 0];
    const float py = x[3 * n + 1];
    const float pz = x[3 * n + 2];
    const float cx = 2.0f * (px - PLO) / (PHI - PLO) - 1.0f;
    const float cy = 2.0f * (py - PLO) / (PHI - PLO) - 1.0f;
    const float cz = 2.0f * (pz - PLO) / (PHI - PLO) - 1.0f;
    const float fx = ((cx + 1.0f) * GD - 1.0f) * 0.5f;
    const float fy = ((cy + 1.0f) * GD - 1.0f) * 0.5f;
    const float fz = ((cz + 1.0f) * GD - 1.0f) * 0.5f;
    const float x0f = floorf(fx), y0f = floorf(fy), z0f = floorf(fz);
    const float wx = fx - x0f, wy = fy - y0f, wz = fz - z0f;
    const int x0 = (int)x0f, y0 = (int)y0f, z0 = (int)z0f;

    float acc[8] = {0.f, 0.f, 0.f, 0.f, 0.f, 0.f, 0.f, 0.f};
#pragma unroll
    for (int dz = 0; dz < 2; ++dz)
#pragma unroll
        for (int dy = 0; dy < 2; ++dy)
#pragma unroll
            for (int dx = 0; dx < 2; ++dx) {
                const int xi = x0 + dx, yi = y0 + dy, zi = z0 + dz;
                const bool valid = ((unsigned)xi < (unsigned)GD) &
                                   ((unsigned)yi < (unsigned)GD) &
                                   ((unsigned)zi < (unsigned)GD);
                float w = (dx ? wx : 1.0f - wx) * (dy ? wy : 1.0f - wy) *
                          (dz ? wz : 1.0f - wz);
                w = valid ? w : 0.0f;
                const int xc = min(max(xi, 0), GD - 1);
                const int yc = min(max(yi, 0), GD - 1);
                const int zc = min(max(zi, 0), GD - 1);
                const size_t idx = (size_t)(zc * GD + yc) * GD + xc;
                const nfloat4 raw = *reinterpret_cast<const nfloat4*>(
                    ft + idx * FD + j * 8);
                const __half2* h2 = reinterpret_cast<const __half2*>(&raw);
#pragma unroll
                for (int k = 0; k < 4; ++k) {
                    const float2 fv = __half22float2(h2[k]);
                    acc[2 * k + 0] = fmaf(fv.x, w, acc[2 * k + 0]);
                    acc[2 * k + 1] = fmaf(fv.y, w, acc[2 * k + 1]);
                }
            }
    float* op = out + (size_t)n * FD + j * 8;
    nfloat4 o0 = {acc[0], acc[1], acc[2], acc[3]};
    nfloat4 o1 = {acc[4], acc[5], acc[6], acc[7]};
    __builtin_nontemporal_store(o0, reinterpret_cast<nfloat4*>(op));
    __builtin_nontemporal_store(o1, reinterpret_cast<nfloat4*>(op) + 1);
}

// ---------------- fallback: direct gather in (C,S) layout ----------------
__global__ __launch_bounds__(256) void trilerp_direct(
    const float* __restrict__ x, const float* __restrict__ f,
    float* __restrict__ out, int npts) {
    const int tid = blockIdx.x * 256 + threadIdx.x;
    const int n = tid >> 3;
    if (n >= npts) return;
    const int j = tid & 7;

    const float px = x[3 * n + 0];
    const float py = x[3 * n + 1];
    const float pz = x[3 * n + 2];
    const float cx = 2.0f * (px - PLO) / (PHI - PLO) - 1.0f;
    const float cy = 2.0f * (py - PLO) / (PHI - PLO) - 1.0f;
    const float cz = 2.0f * (pz - PLO) / (PHI - PLO) - 1.0f;
    const float fx = ((cx + 1.0f) * GD - 1.0f) * 0.5f;
    const float fy = ((cy + 1.0f) * GD - 1.0f) * 0.5f;
    const float fz = ((cz + 1.0f) * GD - 1.0f) * 0.5f;
    const float x0f = floorf(fx), y0f = floorf(fy), z0f = floorf(fz);
    const float wx = fx - x0f, wy = fy - y0f, wz = fz - z0f;
    const int x0 = (int)x0f, y0 = (int)y0f, z0 = (int)z0f;

    float acc[4] = {0.f, 0.f, 0.f, 0.f};
#pragma unroll
    for (int dz = 0; dz < 2; ++dz)
#pragma unroll
        for (int dy = 0; dy < 2; ++dy)
#pragma unroll
            for (int dx = 0; dx < 2; ++dx) {
                const int xi = x0 + dx, yi = y0 + dy, zi = z0 + dz;
                const bool valid = ((unsigned)xi < (unsigned)GD) &
                                   ((unsigned)yi < (unsigned)GD) &
                                   ((unsigned)zi < (unsigned)GD);
                float w = (dx ? wx : 1.0f - wx) * (dy ? wy : 1.0f - wy) *
                          (dz ? wz : 1.0f - wz);
                w = valid ? w : 0.0f;
                const int xc = min(max(xi, 0), GD - 1);
                const int yc = min(max(yi, 0), GD - 1);
                const int zc = min(max(zi, 0), GD - 1);
                const size_t idx = (size_t)(zc * GD + yc) * GD + xc;
#pragma unroll
                for (int k = 0; k < 4; ++k)
                    acc[k] = fmaf(f[(size_t)(j * 4 + k) * SPATIAL + idx], w, acc[k]);
            }
#pragma unroll
    for (int k = 0; k < 4; ++k) out[(size_t)n * FD + j * 4 + k] = acc[k];
}

extern "C" void kernel_launch(void* const* d_in, const int* in_sizes, int n_in,
                              void* d_out, int out_size, void* d_ws, size_t ws_size,
                              hipStream_t stream) {
    const float* x    = (const float*)d_in[0];
    const float* feat = (const float*)d_in[1];
    float*       out  = (float*)d_out;
    const int npts = in_sizes[0] / 3;

    const int nb      = (npts + 255) / 256;      // point blocks
    const int gblocks = (npts * 4 + 255) / 256;  // 4 threads / point

    const size_t FTH_BYTES    = (size_t)SPATIAL * FD * sizeof(__half); // 128 MiB
    const size_t BINNED_OFF   = FTH_BYTES;
    const size_t BINNED_BYTES = (size_t)npts * 16;
    const size_t BH_OFF  = BINNED_OFF + ((BINNED_BYTES + 255) & ~(size_t)255);
    const size_t BH_BYTES = (size_t)NBUCKET * nb * sizeof(int);
    const size_t META_OFF = BH_OFF + ((BH_BYTES + 255) & ~(size_t)255);
    const size_t META_BYTES = 2 * NBUCKET * sizeof(int);
    const size_t need_binned = META_OFF + META_BYTES;

    if (ws_size >= need_binned) {
        __half*  fth    = (__half*)d_ws;
        nfloat4* binned = (nfloat4*)((char*)d_ws + BINNED_OFF);
        int*     bhist  = (int*)((char*)d_ws + BH_OFF);
        int*     binSum = (int*)((char*)d_ws + META_OFF);
        int*     binBase = binSum + NBUCKET;

        transpose_feat_h<<<(int)(SPATIAL / 64), 256, 0, stream>>>(feat, fth);
        hist_blocks<<<nb, 256, 0, stream>>>(x, bhist, npts, nb);
        scan_bins<<<NBUCKET, 256, 0, stream>>>(bhist, binSum, nb);
        scan_bin_totals<<<1, 64, 0, stream>>>(binSum, binBase);
        scatter_det<<<nb, 256, 0, stream>>>(x, bhist, binBase, binned, npts, nb);
        trilerp_bx<<<gblocks, 256, 0, stream>>>(binned, fth, out, npts);
    } else if (ws_size >= FTH_BYTES) {
        __half* fth = (__half*)d_ws;
        transpose_feat_h<<<(int)(SPATIAL / 64), 256, 0, stream>>>(feat, fth);
        trilerp_h<<<gblocks, 256, 0, stream>>>(x, fth, out, npts);
    } else {
        const int dblocks = (npts * 8 + 255) / 256;
        trilerp_direct<<<dblocks, 256, 0, stream>>>(x, feat, out, npts);
    }
}